// Round 9
// baseline (200.061 us; speedup 1.0000x reference)
//
#include <hip/hip_runtime.h>
#include <hip/hip_bf16.h>

// B=2, T=2048, C=1024, H=16, D=64
// qkv = x@w_attn + b_attn ; causal attention ; out = y@w_proj + b_proj
// R9: attn redesigned for exact 8-blocks/CU occupancy: 32-key tiles,
//     LDS = 8(K dbuf)+8(V dbuf)+4(P) = 20 KB, __launch_bounds__(256,8)
//     (VGPR<=64; live set ~50 regs). l accumulated via ones-MFMA (no VALU
//     adds, no final shuffles). Epilogue transpose reuses Kl as scratch.
//     cast+transposes fused into one prep kernel. qkv/proj unchanged (R8).

typedef __attribute__((ext_vector_type(8))) short short8x;   // 8 bf16 (A/B frag)
typedef __attribute__((ext_vector_type(4))) float float4x;   // C/D frag
typedef __attribute__((ext_vector_type(4))) unsigned short ushort4x;
typedef __attribute__((ext_vector_type(2))) unsigned int uint2x;

#define MFMA_BF16 __builtin_amdgcn_mfma_f32_16x16x32_bf16

typedef const __attribute__((address_space(1))) void gvoid_t;
typedef __attribute__((address_space(3))) void lvoid_t;
#define GLOAD_LDS16(g, l) __builtin_amdgcn_global_load_lds((gvoid_t*)(g), (lvoid_t*)(l), 16, 0, 0)

__device__ __forceinline__ unsigned short f2b(float f) {
    unsigned int u = __float_as_uint(f);
    u = (u + 0x7FFFu + ((u >> 16) & 1u)) >> 16;
    return (unsigned short)u;
}
__device__ __forceinline__ unsigned int pk2(float a, float b) {
    return __builtin_amdgcn_perm(__float_as_uint(b) + 0x8000u,
                                 __float_as_uint(a) + 0x8000u, 0x07060302u);
}

// Stage rows [w0,w0+32) of a 64-short-wide tile from global (row stride rs
// shorts) into LDS (stride 64), source-XOR-swizzled: phys chunk c of row R
// holds logical chunk c^(R&7). 4 DMA instrs, 8 rows each.
__device__ __forceinline__ void stage32(const unsigned short* g, size_t rs,
                                        short* ldst, int w0, int lane) {
    const int r8 = lane >> 3;
    const int sc = ((lane & 7) ^ r8) * 8;
#pragma unroll
    for (int q = 0; q < 4; q++) {
        GLOAD_LDS16(g + (size_t)(w0 + q * 8 + r8) * rs + sc,
                    ldst + (w0 + q * 8) * 64);
    }
}

// ---------------------------------------------------------------------------
// prep: fused x cast (blocks 0..4095) + w_attn/w_proj transpose-cast
// (blocks 4096..8191). 256 threads flat.
// ---------------------------------------------------------------------------
__global__ __launch_bounds__(256) void prep(const float* __restrict__ x,
                                            unsigned short* __restrict__ xb,
                                            const float* __restrict__ wa,
                                            unsigned short* __restrict__ waT,
                                            const float* __restrict__ wp,
                                            unsigned short* __restrict__ wpT) {
    __shared__ float tile[32][33];
    const int bid = blockIdx.x;
    const int tid = threadIdx.x;
    if (bid < 4096) {
        int i = bid * 256 + tid;
        float4 v = ((const float4*)x)[i];
        ushort4x o = { f2b(v.x), f2b(v.y), f2b(v.z), f2b(v.w) };
        ((ushort4x*)xb)[i] = o;
        return;
    }
    int b2 = bid - 4096;
    const float* in;
    unsigned short* outp;
    int cols, bx, by;
    if (b2 < 3072) { in = wa; outp = waT; cols = 3072; bx = b2 % 96; by = b2 / 96; }
    else { b2 -= 3072; in = wp; outp = wpT; cols = 1024; bx = b2 & 31; by = b2 >> 5; }
    const int tx = tid & 31, ty = tid >> 5;
    const int cbase = bx * 32, rbase = by * 32;
    const int c = cbase + tx;
    for (int j = 0; j < 32; j += 8)
        tile[ty + j][tx] = in[(size_t)(rbase + ty + j) * cols + c];
    __syncthreads();
    const int rr = rbase + tx;
    for (int j = 0; j < 32; j += 8) {
        int cc = cbase + ty + j;
        outp[(size_t)cc * 1024 + rr] = f2b(tile[tx][ty + j]);
    }
}

// ---------------------------------------------------------------------------
// QKV GEMM: [4096,3072] = xb[4096,1024] @ waT[3072,1024]^T + b_attn
// 128x128 tile, 4 waves 2x2, BK=64, swizzled DMA staging.
// Epilogue: Q (*log2e/8) | K -> QK[4096][2048]; V -> VT[bh][d][t] via LDS.
// ---------------------------------------------------------------------------
__global__ __launch_bounds__(256) void gemm_qkv(const unsigned short* __restrict__ A,
                                                const unsigned short* __restrict__ BT,
                                                const float* __restrict__ bias,
                                                unsigned short* __restrict__ QK,
                                                unsigned short* __restrict__ VTg) {
    __shared__ union {
        struct { short A[128 * 64]; short B[128 * 64]; } s;   // 32 KB
        short vt[4][64 * 80];                                  // 40 KB
    } lds;

    const int K = 1024;
    const int lane = threadIdx.x & 63;
    const int wave = threadIdx.x >> 6;
    const int quad = lane >> 4;
    const int l16  = lane & 15;
    const int sw   = l16 & 7;

    const int rblk = blockIdx.y * 128;
    const int cblk = blockIdx.x * 128;
    const int wr = wave >> 1, wc = wave & 1;

    float4x acc[4][4] = {};

    const unsigned short* Ag = A  + (size_t)rblk * K;
    const unsigned short* Bg = BT + (size_t)cblk * K;

    for (int kk = 0; kk < K; kk += 64) {
        stage32(Ag + kk, K, lds.s.A, wave * 32, lane);
        stage32(Bg + kk, K, lds.s.B, wave * 32, lane);
        __syncthreads();

#pragma unroll
        for (int kk2 = 0; kk2 < 2; kk2++) {
            short8x a[4], b[4];
#pragma unroll
            for (int i = 0; i < 4; i++)
                a[i] = *(const short8x*)&lds.s.A[(wr * 64 + i * 16 + l16) * 64 +
                                                 ((kk2 * 4 + quad) ^ sw) * 8];
#pragma unroll
            for (int j = 0; j < 4; j++)
                b[j] = *(const short8x*)&lds.s.B[(wc * 64 + j * 16 + l16) * 64 +
                                                 ((kk2 * 4 + quad) ^ sw) * 8];
#pragma unroll
            for (int i = 0; i < 4; i++)
#pragma unroll
                for (int j = 0; j < 4; j++)
                    acc[i][j] = MFMA_BF16(a[i], b[j], acc[i][j], 0, 0, 0);
        }
        __syncthreads();
    }

    const int rbase = rblk + wr * 64;
    const int cbase = cblk + wc * 64;

    if (cbase < 2048) {
        const float QS = 0.18033688f;  // log2(e)/8
#pragma unroll
        for (int i = 0; i < 4; i++) {
#pragma unroll
            for (int j = 0; j < 4; j++) {
                int c = cbase + j * 16 + l16;
                float bv = bias[c];
                float sc = (c < 1024) ? QS : 1.0f;
#pragma unroll
                for (int reg = 0; reg < 4; reg++) {
                    int r = rbase + i * 16 + quad * 4 + reg;
                    QK[(size_t)r * 2048 + c] = f2b((acc[i][j][reg] + bv) * sc);
                }
            }
        }
    } else {
#pragma unroll
        for (int i = 0; i < 4; i++) {
#pragma unroll
            for (int j = 0; j < 4; j++) {
                int c = cbase + j * 16 + l16;
                float bv = bias[c];
                uint2x p = { pk2(acc[i][j][0] + bv, acc[i][j][1] + bv),
                             pk2(acc[i][j][2] + bv, acc[i][j][3] + bv) };
                *(uint2x*)&lds.vt[wave][(j * 16 + l16) * 80 + i * 16 + quad * 4] = p;
            }
        }
        const int h   = (cbase - 2048) >> 6;
        const int hb  = (rbase >> 11) * 16 + h;
        const int tb0 = rbase & 2047;
#pragma unroll
        for (int p = 0; p < 8; p++) {
            int dd   = p * 8 + (lane >> 3);
            int toff = (lane & 7) * 8;
            short8x vv = *(const short8x*)&lds.vt[wave][dd * 80 + toff];
            *(short8x*)&VTg[((size_t)(hb * 64 + dd)) * 2048 + tb0 + toff] = vv;
        }
    }
}

// ---------------------------------------------------------------------------
// Proj GEMM: out[4096,1024] = yb @ wpT^T + b_proj (fp32). 64x64 tiles,
// 4 waves stacked in N, BK=64, swizzled staging. grid (16,64) = 1024 blocks.
// ---------------------------------------------------------------------------
__global__ __launch_bounds__(256) void gemm_proj(const unsigned short* __restrict__ A,
                                                 const unsigned short* __restrict__ BT,
                                                 const float* __restrict__ bias,
                                                 float* __restrict__ out) {
    __shared__ struct { short A[64 * 64]; short B[64 * 64]; } lds;  // 16 KB

    const int K = 1024, N = 1024;
    const int lane = threadIdx.x & 63;
    const int wave = threadIdx.x >> 6;
    const int quad = lane >> 4;
    const int l16  = lane & 15;
    const int sw   = l16 & 7;

    const int rblk = blockIdx.y * 64;
    const int cblk = blockIdx.x * 64;

    float4x acc[4] = {};

    const unsigned short* Ag = A  + (size_t)rblk * K;
    const unsigned short* Bg = BT + (size_t)cblk * K;

    for (int kk = 0; kk < K; kk += 64) {
        if (wave < 2) stage32(Ag + kk, K, lds.A, wave * 32, lane);
        else          stage32(Bg + kk, K, lds.B, (wave - 2) * 32, lane);
        __syncthreads();

#pragma unroll
        for (int kk2 = 0; kk2 < 2; kk2++) {
            short8x bfr = *(const short8x*)&lds.B[(wave * 16 + l16) * 64 +
                                                  ((kk2 * 4 + quad) ^ sw) * 8];
#pragma unroll
            for (int i = 0; i < 4; i++) {
                short8x a = *(const short8x*)&lds.A[(i * 16 + l16) * 64 +
                                                    ((kk2 * 4 + quad) ^ sw) * 8];
                acc[i] = MFMA_BF16(a, bfr, acc[i], 0, 0, 0);
            }
        }
        __syncthreads();
    }

    const int c = cblk + wave * 16 + l16;
    const float bv = bias[c];
#pragma unroll
    for (int i = 0; i < 4; i++) {
#pragma unroll
        for (int reg = 0; reg < 4; reg++) {
            int r = rblk + i * 16 + quad * 4 + reg;
            out[(size_t)r * N + c] = acc[i][reg] + bv;
        }
    }
}

// ---------------------------------------------------------------------------
// Flash attention (causal), S^T = K*Q^T, static-max base-2 softmax.
// QK [4096][2048] bf16 (Q pre-scaled log2e/8 | K), VT [bh][64][2048] bf16,
// Y [4096][1024] bf16. Block = 64 q-rows, 4 waves x 16; 32-key tiles double-
// buffered via swizzled DMA. LDS 20 KB, VGPR<=64 -> 8 blocks/CU (32 waves).
// l accumulated by ones-MFMA (C-layout rows all equal l[q]).
// ---------------------------------------------------------------------------
__global__ __launch_bounds__(256, 8) void attn_kernel(const unsigned short* __restrict__ QK,
                                                      const unsigned short* __restrict__ VT,
                                                      unsigned short* __restrict__ Y) {
    __shared__ __attribute__((aligned(16))) short Kl[2][32 * 64];  // 8 KB (also epi scratch)
    __shared__ __attribute__((aligned(16))) short Vl[2][64 * 32];  // 8 KB
    __shared__ __attribute__((aligned(16))) short Pl[4][16 * 32];  // 4 KB

    const int tid  = threadIdx.x;
    const int lane = tid & 63;
    const int wave = tid >> 6;
    const int quad = lane >> 4;
    const int l16  = lane & 15;
    const int sw3  = l16 & 3;
    const int sw7  = l16 & 7;

    const int level = blockIdx.x >> 5;               // 0..31
    const int bh    = blockIdx.x & 31;
    const int pair  = level >> 1;
    const int qb    = (level & 1) ? pair : (31 - pair);  // heavy/light interleave
    const int b = bh >> 4, h = bh & 15;

    const unsigned short* Qp = QK + ((size_t)b * 2048) * 2048 + h * 64;
    const unsigned short* Kp = Qp + 1024;
    const unsigned short* Vp = VT + (size_t)bh * 64 * 2048;

    const int qbase = qb * 64 + wave * 16;
    const int kend  = qbase + 16;
    const int ntb   = 2 * qb + 2;                    // 32-key tiles in block

    short8x aq[2];
#pragma unroll
    for (int kk = 0; kk < 2; kk++)
        aq[kk] = *(const short8x*)(Qp + (size_t)(qbase + l16) * 2048 + kk * 32 + quad * 8);

    // ones A-frag for l accumulation (bf16 1.0 = 0x3F80)
    short8x ones;
#pragma unroll
    for (int e = 0; e < 8; e++) ones[e] = (short)0x3F80;

    // staging source offsets (loop-invariant):
    // K: wave w stages rows w*8..w*8+7 of the 32-row tile (1 DMA)
    const int krow = wave * 8 + (lane >> 3);
    const unsigned short* Kg = Kp + (size_t)krow * 2048 + ((lane & 7) ^ (lane >> 3)) * 8;
    // V: wave w stages rows w*16..w*16+15 of the 64-row tile (1 DMA)
    const int vrow = wave * 16 + (lane >> 2);
    const unsigned short* Vg = Vp + (size_t)vrow * 2048 + (((lane & 3) ^ ((lane >> 2) & 3)) * 8);

    // prologue: stage tile 0 into buf 0
    GLOAD_LDS16(Kg, &Kl[0][wave * 8 * 64]);
    GLOAD_LDS16(Vg, &Vl[0][wave * 16 * 32]);
    __syncthreads();

    float4x O[4] = {};
    float4x lacc = {};

    for (int it = 0; it < ntb; it++) {
        const int kb = it * 32;
        const short* Kc = Kl[it & 1];
        const short* Vc = Vl[it & 1];

        if (it + 1 < ntb) {
            GLOAD_LDS16(Kg + (size_t)(kb + 32) * 2048, &Kl[(it + 1) & 1][wave * 8 * 64]);
            GLOAD_LDS16(Vg + (kb + 32), &Vl[(it + 1) & 1][wave * 16 * 32]);
        }

        if (kb < kend) {
            float4x S[2];
#pragma unroll
            for (int t = 0; t < 2; t++) {
                short8x kf0 = *(const short8x*)&Kc[(t * 16 + l16) * 64 + ((quad) ^ sw7) * 8];
                short8x kf1 = *(const short8x*)&Kc[(t * 16 + l16) * 64 + ((4 + quad) ^ sw7) * 8];
                S[t] = (float4x){0.f, 0.f, 0.f, 0.f};
                S[t] = MFMA_BF16(kf0, aq[0], S[t], 0, 0, 0);
                S[t] = MFMA_BF16(kf1, aq[1], S[t], 0, 0, 0);
            }

            if (kb + 32 > qbase) {
                int q = qbase + l16;
#pragma unroll
                for (int t = 0; t < 2; t++)
#pragma unroll
                    for (int reg = 0; reg < 4; reg++)
                        if (kb + t * 16 + quad * 4 + reg > q) S[t][reg] = -1e38f;
            }

#pragma unroll
            for (int t = 0; t < 2; t++) {
                float e0 = __builtin_amdgcn_exp2f(S[t][0]);
                float e1 = __builtin_amdgcn_exp2f(S[t][1]);
                float e2 = __builtin_amdgcn_exp2f(S[t][2]);
                float e3 = __builtin_amdgcn_exp2f(S[t][3]);
                // P^T row l16 (32 keys, 4 chunks of 16B), chunk swizzle ^sw3
                uint2x p = { pk2(e0, e1), pk2(e2, e3) };
                *(uint2x*)&Pl[wave][l16 * 32 + ((t * 2 + (quad >> 1)) ^ sw3) * 8 + (quad & 1) * 4] = p;
            }

            short8x bp = *(const short8x*)&Pl[wave][l16 * 32 + (quad ^ sw3) * 8];
            lacc = MFMA_BF16(ones, bp, lacc, 0, 0, 0);
#pragma unroll
            for (int dt = 0; dt < 4; dt++) {
                short8x vf = *(const short8x*)&Vc[(dt * 16 + l16) * 32 + (quad ^ sw3) * 8];
                O[dt] = MFMA_BF16(vf, bp, O[dt], 0, 0, 0);
            }
        }
        __syncthreads();
    }

    // epilogue: rl from lacc (all regs hold l[q]); transpose via Kl scratch
    float rl = 1.0f / lacc[0];
    short* scr = &Kl[0][0] + wave * 1024;   // 16 rows x 64 shorts, wave-private
#pragma unroll
    for (int dt = 0; dt < 4; dt++) {
        uint2x o = { pk2(O[dt][0] * rl, O[dt][1] * rl),
                     pk2(O[dt][2] * rl, O[dt][3] * rl) };
        *(uint2x*)&scr[l16 * 64 + ((2 * dt + (quad >> 1)) ^ sw7) * 8 + (quad & 1) * 4] = o;
    }
    const int t = qbase + l16;
#pragma unroll
    for (int cc = 0; cc < 2; cc++) {
        short8x row = *(const short8x*)&scr[l16 * 64 + ((2 * quad + cc) ^ sw7) * 8];
        *(short8x*)&Y[((size_t)(b * 2048 + t)) * 1024 + h * 64 + (2 * quad + cc) * 8] = row;
    }
}

// ---------------------------------------------------------------------------
extern "C" void kernel_launch(void* const* d_in, const int* in_sizes, int n_in,
                              void* d_out, int out_size, void* d_ws, size_t ws_size,
                              hipStream_t stream) {
    const float* x      = (const float*)d_in[0];
    const float* w_attn = (const float*)d_in[1];
    const float* b_attn = (const float*)d_in[2];
    const float* w_proj = (const float*)d_in[3];
    const float* b_proj = (const float*)d_in[4];
    float* out = (float*)d_out;

    char* ws = (char*)d_ws;
    unsigned short* xb  = (unsigned short*)(ws + (size_t)0);          // 8 MB [4096,1024]
    unsigned short* waT = (unsigned short*)(ws + (size_t)(8  << 20)); // 6 MB [3072,1024]
    unsigned short* wpT = (unsigned short*)(ws + (size_t)(14 << 20)); // 2 MB [1024,1024]
    unsigned short* QKb = (unsigned short*)(ws + (size_t)(16 << 20)); // 16 MB [4096,2048]
    unsigned short* VTb = (unsigned short*)(ws + (size_t)(32 << 20)); // 8 MB [B,H,64,2048]
    unsigned short* yb  = (unsigned short*)(ws + (size_t)(40 << 20)); // 8 MB [4096,1024]

    prep<<<8192, 256, 0, stream>>>(x, xb, w_attn, waT, w_proj, wpT);

    gemm_qkv<<<dim3(24, 32), 256, 0, stream>>>(xb, waT, b_attn, QKb, VTb);

    attn_kernel<<<1024, 256, 0, stream>>>(QKb, VTb, yb);

    gemm_proj<<<dim3(16, 64), 256, 0, stream>>>(yb, wpT, b_proj, out);
}

// Round 10
// 191.175 us; speedup vs baseline: 1.0465x; 1.0465x over previous
//
#include <hip/hip_runtime.h>
#include <hip/hip_bf16.h>

// B=2, T=2048, C=1024, H=16, D=64
// qkv = x@w_attn + b_attn ; causal attention ; out = y@w_proj + b_proj
// R10: attn at 28 KB LDS -> 5 blocks/CU: K tiles 32-key (rows 64-short wide,
//      conflict-free) dbuf 2x4KB; V tiles 64-key dbuf 2x8KB staged every other
//      iter (2-iter prefetch slack); P 4KB. NO launch_bounds clamp (R6/R9
//      spill lesson); rows never narrower than 128B (R9 conflict lesson).
//      prep/gemm_qkv/gemm_proj = R8 (known good).

typedef __attribute__((ext_vector_type(8))) short short8x;   // 8 bf16 (A/B frag)
typedef __attribute__((ext_vector_type(4))) float float4x;   // C/D frag
typedef __attribute__((ext_vector_type(4))) unsigned short ushort4x;
typedef __attribute__((ext_vector_type(2))) unsigned int uint2x;

#define MFMA_BF16 __builtin_amdgcn_mfma_f32_16x16x32_bf16

typedef const __attribute__((address_space(1))) void gvoid_t;
typedef __attribute__((address_space(3))) void lvoid_t;
#define GLOAD_LDS16(g, l) __builtin_amdgcn_global_load_lds((gvoid_t*)(g), (lvoid_t*)(l), 16, 0, 0)

__device__ __forceinline__ unsigned short f2b(float f) {
    unsigned int u = __float_as_uint(f);
    u = (u + 0x7FFFu + ((u >> 16) & 1u)) >> 16;
    return (unsigned short)u;
}
__device__ __forceinline__ unsigned int pk2(float a, float b) {
    return __builtin_amdgcn_perm(__float_as_uint(b) + 0x8000u,
                                 __float_as_uint(a) + 0x8000u, 0x07060302u);
}

// Stage rows [w0,w0+32) of a 64-short-wide tile from global (row stride rs
// shorts) into LDS (stride 64), source-XOR-swizzled: phys chunk c of row R
// holds logical chunk c^(R&7). 4 DMA instrs, 8 rows each.
__device__ __forceinline__ void stage32(const unsigned short* g, size_t rs,
                                        short* ldst, int w0, int lane) {
    const int r8 = lane >> 3;
    const int sc = ((lane & 7) ^ r8) * 8;
#pragma unroll
    for (int q = 0; q < 4; q++) {
        GLOAD_LDS16(g + (size_t)(w0 + q * 8 + r8) * rs + sc,
                    ldst + (w0 + q * 8) * 64);
    }
}

// ---------------------------------------------------------------------------
// prep: fused x cast (blocks 0..4095) + w_attn/w_proj transpose-cast.
// ---------------------------------------------------------------------------
__global__ __launch_bounds__(256) void prep(const float* __restrict__ x,
                                            unsigned short* __restrict__ xb,
                                            const float* __restrict__ wa,
                                            unsigned short* __restrict__ waT,
                                            const float* __restrict__ wp,
                                            unsigned short* __restrict__ wpT) {
    __shared__ float tile[32][33];
    const int bid = blockIdx.x;
    const int tid = threadIdx.x;
    if (bid < 4096) {
        int i = bid * 256 + tid;
        float4 v = ((const float4*)x)[i];
        ushort4x o = { f2b(v.x), f2b(v.y), f2b(v.z), f2b(v.w) };
        ((ushort4x*)xb)[i] = o;
        return;
    }
    int b2 = bid - 4096;
    const float* in;
    unsigned short* outp;
    int cols, bx, by;
    if (b2 < 3072) { in = wa; outp = waT; cols = 3072; bx = b2 % 96; by = b2 / 96; }
    else { b2 -= 3072; in = wp; outp = wpT; cols = 1024; bx = b2 & 31; by = b2 >> 5; }
    const int tx = tid & 31, ty = tid >> 5;
    const int cbase = bx * 32, rbase = by * 32;
    const int c = cbase + tx;
    for (int j = 0; j < 32; j += 8)
        tile[ty + j][tx] = in[(size_t)(rbase + ty + j) * cols + c];
    __syncthreads();
    const int rr = rbase + tx;
    for (int j = 0; j < 32; j += 8) {
        int cc = cbase + ty + j;
        outp[(size_t)cc * 1024 + rr] = f2b(tile[tx][ty + j]);
    }
}

// ---------------------------------------------------------------------------
// QKV GEMM: [4096,3072] = xb[4096,1024] @ waT[3072,1024]^T + b_attn
// 128x128 tile, 4 waves 2x2, BK=64, swizzled DMA staging.
// Epilogue: Q (*log2e/8) | K -> QK[4096][2048]; V -> VT[bh][d][t] via LDS.
// ---------------------------------------------------------------------------
__global__ __launch_bounds__(256) void gemm_qkv(const unsigned short* __restrict__ A,
                                                const unsigned short* __restrict__ BT,
                                                const float* __restrict__ bias,
                                                unsigned short* __restrict__ QK,
                                                unsigned short* __restrict__ VTg) {
    __shared__ union {
        struct { short A[128 * 64]; short B[128 * 64]; } s;   // 32 KB
        short vt[4][64 * 80];                                  // 40 KB
    } lds;

    const int K = 1024;
    const int lane = threadIdx.x & 63;
    const int wave = threadIdx.x >> 6;
    const int quad = lane >> 4;
    const int l16  = lane & 15;
    const int sw   = l16 & 7;

    const int rblk = blockIdx.y * 128;
    const int cblk = blockIdx.x * 128;
    const int wr = wave >> 1, wc = wave & 1;

    float4x acc[4][4] = {};

    const unsigned short* Ag = A  + (size_t)rblk * K;
    const unsigned short* Bg = BT + (size_t)cblk * K;

    for (int kk = 0; kk < K; kk += 64) {
        stage32(Ag + kk, K, lds.s.A, wave * 32, lane);
        stage32(Bg + kk, K, lds.s.B, wave * 32, lane);
        __syncthreads();

#pragma unroll
        for (int kk2 = 0; kk2 < 2; kk2++) {
            short8x a[4], b[4];
#pragma unroll
            for (int i = 0; i < 4; i++)
                a[i] = *(const short8x*)&lds.s.A[(wr * 64 + i * 16 + l16) * 64 +
                                                 ((kk2 * 4 + quad) ^ sw) * 8];
#pragma unroll
            for (int j = 0; j < 4; j++)
                b[j] = *(const short8x*)&lds.s.B[(wc * 64 + j * 16 + l16) * 64 +
                                                 ((kk2 * 4 + quad) ^ sw) * 8];
#pragma unroll
            for (int i = 0; i < 4; i++)
#pragma unroll
                for (int j = 0; j < 4; j++)
                    acc[i][j] = MFMA_BF16(a[i], b[j], acc[i][j], 0, 0, 0);
        }
        __syncthreads();
    }

    const int rbase = rblk + wr * 64;
    const int cbase = cblk + wc * 64;

    if (cbase < 2048) {
        const float QS = 0.18033688f;  // log2(e)/8
#pragma unroll
        for (int i = 0; i < 4; i++) {
#pragma unroll
            for (int j = 0; j < 4; j++) {
                int c = cbase + j * 16 + l16;
                float bv = bias[c];
                float sc = (c < 1024) ? QS : 1.0f;
#pragma unroll
                for (int reg = 0; reg < 4; reg++) {
                    int r = rbase + i * 16 + quad * 4 + reg;
                    QK[(size_t)r * 2048 + c] = f2b((acc[i][j][reg] + bv) * sc);
                }
            }
        }
    } else {
#pragma unroll
        for (int i = 0; i < 4; i++) {
#pragma unroll
            for (int j = 0; j < 4; j++) {
                int c = cbase + j * 16 + l16;
                float bv = bias[c];
                uint2x p = { pk2(acc[i][j][0] + bv, acc[i][j][1] + bv),
                             pk2(acc[i][j][2] + bv, acc[i][j][3] + bv) };
                *(uint2x*)&lds.vt[wave][(j * 16 + l16) * 80 + i * 16 + quad * 4] = p;
            }
        }
        const int h   = (cbase - 2048) >> 6;
        const int hb  = (rbase >> 11) * 16 + h;
        const int tb0 = rbase & 2047;
#pragma unroll
        for (int p = 0; p < 8; p++) {
            int dd   = p * 8 + (lane >> 3);
            int toff = (lane & 7) * 8;
            short8x vv = *(const short8x*)&lds.vt[wave][dd * 80 + toff];
            *(short8x*)&VTg[((size_t)(hb * 64 + dd)) * 2048 + tb0 + toff] = vv;
        }
    }
}

// ---------------------------------------------------------------------------
// Proj GEMM: out[4096,1024] = yb @ wpT^T + b_proj (fp32). 64x64 tiles,
// 4 waves stacked in N, BK=64, swizzled staging. grid (16,64) = 1024 blocks.
// ---------------------------------------------------------------------------
__global__ __launch_bounds__(256) void gemm_proj(const unsigned short* __restrict__ A,
                                                 const unsigned short* __restrict__ BT,
                                                 const float* __restrict__ bias,
                                                 float* __restrict__ out) {
    __shared__ struct { short A[64 * 64]; short B[64 * 64]; } lds;  // 16 KB

    const int K = 1024, N = 1024;
    const int lane = threadIdx.x & 63;
    const int wave = threadIdx.x >> 6;
    const int quad = lane >> 4;
    const int l16  = lane & 15;
    const int sw   = l16 & 7;

    const int rblk = blockIdx.y * 64;
    const int cblk = blockIdx.x * 64;

    float4x acc[4] = {};

    const unsigned short* Ag = A  + (size_t)rblk * K;
    const unsigned short* Bg = BT + (size_t)cblk * K;

    for (int kk = 0; kk < K; kk += 64) {
        if (wave < 2) stage32(Ag + kk, K, lds.A, wave * 32, lane);
        else          stage32(Bg + kk, K, lds.B, (wave - 2) * 32, lane);
        __syncthreads();

#pragma unroll
        for (int kk2 = 0; kk2 < 2; kk2++) {
            short8x bfr = *(const short8x*)&lds.B[(wave * 16 + l16) * 64 +
                                                  ((kk2 * 4 + quad) ^ sw) * 8];
#pragma unroll
            for (int i = 0; i < 4; i++) {
                short8x a = *(const short8x*)&lds.A[(i * 16 + l16) * 64 +
                                                    ((kk2 * 4 + quad) ^ sw) * 8];
                acc[i] = MFMA_BF16(a, bfr, acc[i], 0, 0, 0);
            }
        }
        __syncthreads();
    }

    const int c = cblk + wave * 16 + l16;
    const float bv = bias[c];
#pragma unroll
    for (int i = 0; i < 4; i++) {
#pragma unroll
        for (int reg = 0; reg < 4; reg++) {
            int r = rblk + i * 16 + quad * 4 + reg;
            out[(size_t)r * N + c] = acc[i][reg] + bv;
        }
    }
}

// ---------------------------------------------------------------------------
// Flash attention (causal), S^T = K*Q^T, static-max base-2 softmax.
// QK [4096][2048] bf16 (Q pre-scaled log2e/8 | K), VT [bh][64][2048] bf16,
// Y [4096][1024] bf16. Block = 64 q-rows, 4 waves x 16 rows.
// K: 32-key tiles (32x64 shorts, 4 KB) double-buffered, staged every iter
//    (256 thr x 1 DMA). V: 64-key windows (64x64, 8 KB) double-buffered,
//    staged every OTHER iter (2 DMA/thr) -> 2-iter prefetch slack.
// LDS 28 KB -> 5 blocks/CU. All LDS rows 128 B wide (conflict-free swizzle),
// except P (32-wide, 5 ops/tile, tolerable). No launch_bounds clamp.
// ---------------------------------------------------------------------------
__global__ __launch_bounds__(256) void attn_kernel(const unsigned short* __restrict__ QK,
                                                   const unsigned short* __restrict__ VT,
                                                   unsigned short* __restrict__ Y) {
    __shared__ __attribute__((aligned(16))) short Kl[2][32 * 64];  //  8 KB (epi scratch too)
    __shared__ __attribute__((aligned(16))) short Vl[2][64 * 64];  // 16 KB
    __shared__ __attribute__((aligned(16))) short Pl[4][16 * 32];  //  4 KB

    const int tid  = threadIdx.x;
    const int lane = tid & 63;
    const int wave = tid >> 6;
    const int quad = lane >> 4;
    const int l16  = lane & 15;
    const int sw3  = l16 & 3;
    const int sw7  = l16 & 7;

    const int level = blockIdx.x >> 5;               // 0..31
    const int bh    = blockIdx.x & 31;
    const int pair  = level >> 1;
    const int qb    = (level & 1) ? pair : (31 - pair);  // heavy/light interleave
    const int b = bh >> 4, h = bh & 15;

    const unsigned short* Qp = QK + ((size_t)b * 2048) * 2048 + h * 64;
    const unsigned short* Kp = Qp + 1024;
    const unsigned short* Vp = VT + (size_t)bh * 64 * 2048;

    const int qbase = qb * 64 + wave * 16;
    const int kend  = qbase + 16;
    const int ntb   = 2 * qb + 2;                    // 32-key tiles
    const int nvw   = qb + 1;                        // 64-key V windows

    short8x aq[2];
#pragma unroll
    for (int kk = 0; kk < 2; kk++)
        aq[kk] = *(const short8x*)(Qp + (size_t)(qbase + l16) * 2048 + kk * 32 + quad * 8);

    // per-thread staging source (loop-invariant):
    // K 32x64 tile: thread t -> row t>>3 (0..31), chunk (t&7)^(row&7)
    const int kRow = tid >> 3;
    const int kOff = ((tid & 7) ^ (kRow & 7)) * 8;
    const unsigned short* Ksrc = Kp + (size_t)kRow * 2048 + kOff;   // + key*2048
    // V 64x64 window: thread t -> rows t>>3 and 32+(t>>3), same chunk xor
    const unsigned short* Vsrc0 = Vp + (size_t)kRow * 2048 + kOff;        // + keybase
    const unsigned short* Vsrc1 = Vp + (size_t)(kRow + 32) * 2048 + kOff; // + keybase

    // prologue: K tile 0 -> Kl[0]; V window 0 -> Vl[0]
    GLOAD_LDS16(Ksrc, &Kl[0][wave * 512]);
    GLOAD_LDS16(Vsrc0, &Vl[0][wave * 512]);
    GLOAD_LDS16(Vsrc1, &Vl[0][2048 + wave * 512]);
    __syncthreads();

    float l = 0.f;
    float4x O[4] = {};

    for (int it = 0; it < ntb; it++) {
        const int kb = it * 32;
        const short* Kc = Kl[it & 1];
        const short* Vc = Vl[(it >> 1) & 1];
        const int vh = (it & 1) * 4;                 // V chunk base within window

        // prefetch: K tile it+1 every iter; V window (it>>1)+1 on even iters
        if (it + 1 < ntb)
            GLOAD_LDS16(Ksrc + (size_t)(kb + 32) * 2048, &Kl[(it + 1) & 1][wave * 512]);
        if (!(it & 1) && (it >> 1) + 1 < nvw) {
            const int keyb = ((it >> 1) + 1) * 64;
            short* vd = Vl[((it >> 1) + 1) & 1];
            GLOAD_LDS16(Vsrc0 + keyb, &vd[wave * 512]);
            GLOAD_LDS16(Vsrc1 + keyb, &vd[2048 + wave * 512]);
        }

        if (kb < kend) {
            float4x S[2];
#pragma unroll
            for (int t = 0; t < 2; t++) {
                short8x kf0 = *(const short8x*)&Kc[(t * 16 + l16) * 64 + ((quad) ^ sw7) * 8];
                short8x kf1 = *(const short8x*)&Kc[(t * 16 + l16) * 64 + ((4 + quad) ^ sw7) * 8];
                S[t] = (float4x){0.f, 0.f, 0.f, 0.f};
                S[t] = MFMA_BF16(kf0, aq[0], S[t], 0, 0, 0);
                S[t] = MFMA_BF16(kf1, aq[1], S[t], 0, 0, 0);
            }

            if (kb + 32 > qbase) {
                int q = qbase + l16;
#pragma unroll
                for (int t = 0; t < 2; t++)
#pragma unroll
                    for (int reg = 0; reg < 4; reg++)
                        if (kb + t * 16 + quad * 4 + reg > q) S[t][reg] = -1e38f;
            }

#pragma unroll
            for (int t = 0; t < 2; t++) {
                float e0 = __builtin_amdgcn_exp2f(S[t][0]);
                float e1 = __builtin_amdgcn_exp2f(S[t][1]);
                float e2 = __builtin_amdgcn_exp2f(S[t][2]);
                float e3 = __builtin_amdgcn_exp2f(S[t][3]);
                l += (e0 + e1) + (e2 + e3);
                uint2x p = { pk2(e0, e1), pk2(e2, e3) };
                *(uint2x*)&Pl[wave][l16 * 32 + ((t * 2 + (quad >> 1)) ^ sw3) * 8 + (quad & 1) * 4] = p;
            }

            short8x bp = *(const short8x*)&Pl[wave][l16 * 32 + (quad ^ sw3) * 8];
#pragma unroll
            for (int dt = 0; dt < 4; dt++) {
                short8x vf = *(const short8x*)&Vc[(dt * 16 + l16) * 64 + ((vh + quad) ^ sw7) * 8];
                O[dt] = MFMA_BF16(vf, bp, O[dt], 0, 0, 0);
            }
        }
        __syncthreads();
    }

    // epilogue: reduce l across quads, normalize, transpose via Kl scratch
    float lv = l;
    lv += __shfl_xor(lv, 16, 64);
    lv += __shfl_xor(lv, 32, 64);
    float rl = 1.0f / lv;
    short* scr = &Kl[0][0] + wave * 1024;   // 16 rows x 64 shorts, wave-private
#pragma unroll
    for (int dt = 0; dt < 4; dt++) {
        uint2x o = { pk2(O[dt][0] * rl, O[dt][1] * rl),
                     pk2(O[dt][2] * rl, O[dt][3] * rl) };
        *(uint2x*)&scr[l16 * 64 + ((2 * dt + (quad >> 1)) ^ sw7) * 8 + (quad & 1) * 4] = o;
    }
    const int t = qbase + l16;
#pragma unroll
    for (int cc = 0; cc < 2; cc++) {
        short8x row = *(const short8x*)&scr[l16 * 64 + ((2 * quad + cc) ^ sw7) * 8];
        *(short8x*)&Y[((size_t)(b * 2048 + t)) * 1024 + h * 64 + (2 * quad + cc) * 8] = row;
    }
}

// ---------------------------------------------------------------------------
extern "C" void kernel_launch(void* const* d_in, const int* in_sizes, int n_in,
                              void* d_out, int out_size, void* d_ws, size_t ws_size,
                              hipStream_t stream) {
    const float* x      = (const float*)d_in[0];
    const float* w_attn = (const float*)d_in[1];
    const float* b_attn = (const float*)d_in[2];
    const float* w_proj = (const float*)d_in[3];
    const float* b_proj = (const float*)d_in[4];
    float* out = (float*)d_out;

    char* ws = (char*)d_ws;
    unsigned short* xb  = (unsigned short*)(ws + (size_t)0);          // 8 MB [4096,1024]
    unsigned short* waT = (unsigned short*)(ws + (size_t)(8  << 20)); // 6 MB [3072,1024]
    unsigned short* wpT = (unsigned short*)(ws + (size_t)(14 << 20)); // 2 MB [1024,1024]
    unsigned short* QKb = (unsigned short*)(ws + (size_t)(16 << 20)); // 16 MB [4096,2048]
    unsigned short* VTb = (unsigned short*)(ws + (size_t)(32 << 20)); // 8 MB [B,H,64,2048]
    unsigned short* yb  = (unsigned short*)(ws + (size_t)(40 << 20)); // 8 MB [4096,1024]

    prep<<<8192, 256, 0, stream>>>(x, xb, w_attn, waT, w_proj, wpT);

    gemm_qkv<<<dim3(24, 32), 256, 0, stream>>>(xb, waT, b_attn, QKb, VTb);

    attn_kernel<<<1024, 256, 0, stream>>>(QKb, VTb, yb);

    gemm_proj<<<dim3(16, 64), 256, 0, stream>>>(yb, wpT, b_proj, out);
}